// Round 4
// baseline (1368.569 us; speedup 1.0000x reference)
//
#include <hip/hip_runtime.h>
#include <stdint.h>

// ---------------------------------------------------------------------------
// FixedPointLSTM (B=64, T=256, I=512, H=1024), fixed-point Q8.8 with hard
// activations. All fxp grid values are exactly representable in fp16; fp16
// MFMA with fp32 accumulate matches the numpy reference to ~1 grid step.
//
// R14 = R13 (862 us lstm / 1063 us total) + chunk-granular step pipeline.
// History: R11 (sc0 intra-XCD) FAILED; R12 (vmcnt placement) regressed;
// R13 (coalesced h publication) -7 us -> store path is off the critical
// path. Remaining cost is the lock-step skeleton: max-over-32-flag poll ->
// barrier -> stage-all -> barrier -> compute.
// R14 exploits: MFMA k-chunk kt consumes exactly rank kt's h slice. New step:
//  * wave w polls only ITS 8 producers (flags 8w..8w+7, 4 u64),
//  * stages its 4 column-pairs (8x8B loads, 128B runs -> ds_write_b64),
//  * publishes per-pair LDS rdy[p]=t+1 (monotone counters, no reset),
//  * all waves consume pairs p=0..15 in fixed order (compile-time B-frag
//    indices), gated by ~60cyc LDS rdy polls instead of block barriers.
// Barriers B and C are GONE (1 __syncthreads/step instead of 3); discovery
// is 4-way parallel; a straggler rank delays one chunk, not the whole stage.
// Accumulation order, fragment layout, gates, R13 h-publication, barrier A,
// agent-scope flag protocol: unchanged.
// ---------------------------------------------------------------------------

typedef _Float16 h8 __attribute__((ext_vector_type(8)));
typedef _Float16 h4 __attribute__((ext_vector_type(4)));
typedef float f4 __attribute__((ext_vector_type(4)));
typedef unsigned long long u64;

#define MFMA16(a, b, c) __builtin_amdgcn_mfma_f32_16x16x32_f16(a, b, c, 0, 0, 0)

__device__ __forceinline__ float fxp(float x) {
  float q = rintf(x * 256.0f) * 0.00390625f;
  return fminf(fmaxf(q, -128.0f), 127.99609375f);
}

// round-only: for values provably in [-128, 127.996] the clamp is a no-op.
__device__ __forceinline__ float fxp_rnd(float x) {
  return rintf(x * 256.0f) * 0.00390625f;
}

__device__ __forceinline__ float hsig(float x) {
  return fminf(fmaxf(x / 6.0f + 0.5f, 0.0f), 1.0f);  // IEEE div to match np
}

// ---- quantize fp32 -> fxp grid, store fp16 ---------------------------------
__global__ void qf16_kernel(const float* __restrict__ in,
                            _Float16* __restrict__ out, int n4) {
  int i = blockIdx.x * 256 + threadIdx.x;
  if (i < n4) {
    float4 v = ((const float4*)in)[i];
    h4 o;
    o[0] = (_Float16)fxp(v.x); o[1] = (_Float16)fxp(v.y);
    o[2] = (_Float16)fxp(v.z); o[3] = (_Float16)fxp(v.w);
    ((h4*)out)[i] = o;
  }
}

// quantize + transpose x: in [64][256][512] -> rows m = t*64+b, [16384][512]
__global__ void qx_kernel(const float* __restrict__ in,
                          _Float16* __restrict__ out) {
  int i4 = blockIdx.x * 256 + threadIdx.x;  // over 16384*128 float4s
  int col4 = i4 & 127;
  int row = i4 >> 7;  // b*256 + t
  int b = row >> 8, tt = row & 255;
  float4 v = ((const float4*)in)[i4];
  h4 o;
  o[0] = (_Float16)fxp(v.x); o[1] = (_Float16)fxp(v.y);
  o[2] = (_Float16)fxp(v.z); o[3] = (_Float16)fxp(v.w);
  ((h4*)out)[(size_t)((tt << 6) + b) * 128 + col4] = o;
}

__global__ void qf32_kernel(const float* __restrict__ in,
                            float* __restrict__ out, int n4) {
  int i = blockIdx.x * 256 + threadIdx.x;
  if (i < n4) {
    float4 v = ((const float4*)in)[i];
    float4 o;
    o.x = fxp(v.x); o.y = fxp(v.y); o.z = fxp(v.z); o.w = fxp(v.w);
    ((float4*)out)[i] = o;
  }
}

// h0 -> hbuf buffer 0, layout [grp=8][buf=2][row=8][1024] fp16
__global__ void qh0_kernel(const float* __restrict__ in,
                           _Float16* __restrict__ hbuf) {
  int i = blockIdx.x * 256 + threadIdx.x;  // over 64*1024/4
  int col4 = i & 255, b = i >> 8;
  float4 v = ((const float4*)in)[i];
  h4 o;
  o[0] = (_Float16)fxp(v.x); o[1] = (_Float16)fxp(v.y);
  o[2] = (_Float16)fxp(v.z); o[3] = (_Float16)fxp(v.w);
  *(h4*)(hbuf + (size_t)(b >> 3) * 16384 + (b & 7) * 1024 + col4 * 4) = o;
}

// ---- async global->LDS helper (width 16B; LDS dest = wave-uniform base) ----
__device__ __forceinline__ void gload_lds16(const _Float16* g, _Float16* l) {
  __builtin_amdgcn_global_load_lds(
      (const __attribute__((address_space(1))) uint32_t*)g,
      (__attribute__((address_space(3))) uint32_t*)l, 16, 0, 0);
}

// ---------------------------------------------------------------------------
// gx = fxp(x_q @ w_ih_q^T + b_ih_q), packed [T=256][oct=8][rank=32][slot=128][8]
// fp16 (128 MB). slot = (w<<5)|(qh<<4)|(gate&1)<<3|(j&7); per-entry 8 fp16 =
// [tile0 r=0..3 | tile1 r=0..3], tile = gate>>1, r = b&3, qh = (b>>2)&1.
// ---------------------------------------------------------------------------
__global__ __launch_bounds__(256) void gemm_gx_kernel(
    const _Float16* __restrict__ Xq,   // [16384][512], m = t*64+b
    const _Float16* __restrict__ Wih,  // [4096][512]
    const float* __restrict__ bih,     // [4096]
    _Float16* __restrict__ gx)         // packed, see above
{
  __shared__ _Float16 As[128 * 32];
  __shared__ _Float16 Bs[128 * 32];
  const int tid = threadIdx.x;
  const int lane = tid & 63;
  const int w = tid >> 6;
  const int wm = (w >> 1) * 64;
  const int wn = (w & 1) * 64;
  const int m0 = blockIdx.x * 128;
  const int n0 = blockIdx.y * 128;
  const int cl = lane & 15, q = lane >> 4;

  f4 acc[4][4] = {};

  for (int k0 = 0; k0 < 512; k0 += 32) {
#pragma unroll
    for (int i = 0; i < 2; i++) {
      int idx = i * 256 + tid;
      int row = idx >> 2;
      int kc = (idx & 3) << 3;
      int wbase = (i * 256 + (tid & 192)) << 3;  // wave-uniform LDS base
      gload_lds16(Xq + (size_t)(m0 + row) * 512 + k0 + kc, As + wbase);
      gload_lds16(Wih + (size_t)(n0 + row) * 512 + k0 + kc, Bs + wbase);
    }
    __syncthreads();
    h8 af[4], bf[4];
#pragma unroll
    for (int mt = 0; mt < 4; mt++)
      af[mt] = *(const h8*)(As + (wm + mt * 16 + cl) * 32 + q * 8);
#pragma unroll
    for (int nt = 0; nt < 4; nt++)
      bf[nt] = *(const h8*)(Bs + (wn + nt * 16 + cl) * 32 + q * 8);
#pragma unroll
    for (int mt = 0; mt < 4; mt++)
#pragma unroll
      for (int nt = 0; nt < 4; nt++)
        acc[mt][nt] = MFMA16(af[mt], bf[nt], acc[mt][nt]);
    __syncthreads();
  }

  const int g = n0 >> 10;  // whole n-block lies in one gate
  const int tile = g >> 1, g1 = g & 1;
#pragma unroll
  for (int nt = 0; nt < 4; nt++) {
    const int n = n0 + wn + nt * 16 + cl;
    const float bv = bih[n];
    const int j = n & 1023;
    const int rank = j >> 5, wq = (j >> 3) & 3, c7 = j & 7;
#pragma unroll
    for (int mt = 0; mt < 4; mt++) {
      const int m = m0 + wm + mt * 16 + q * 4;  // 4-aligned
      const int b = m & 63, tt = m >> 6;
      const int oct = b >> 3, qh = (b >> 2) & 1;
      const int slot = (wq << 5) | (qh << 4) | (g1 << 3) | c7;
      h4 pk;
#pragma unroll
      for (int r = 0; r < 4; r++) pk[r] = (_Float16)fxp(acc[mt][nt][r] + bv);
      *(h4*)(gx + ((((size_t)tt * 8 + oct) * 32 + rank) * 128 + slot) * 8 +
             tile * 4) = pk;
    }
  }
}

// ---------------------------------------------------------------------------
// Persistent recurrence. 256 blocks x 256 threads, a255 pin -> 1 block/CU ->
// all blocks co-resident. Block = (grp = blockIdx&7, rank = blockIdx>>3);
// group owns batch rows 8g..8g+7; rank owns h-cols rank*32..+31 x 4 gates
// (128 W_hh rows in regs). Per step (R14 chunked pipeline):
//   gx prefetch -> [per wave] poll own 4 pair-flags -> stage own 4 column-
//   pairs (8x8B agent loads, 128B runs -> ds_write_b64, 4-way banks) ->
//   lgkmcnt -> rdy[p]=t+1 -> consume pairs 0..15 (LDS rdy gate + ds_read +
//   4 MFMA each) -> gates -> h tile publication (R13) -> barrier A (drains
//   h stores) -> tid0 flag -> out stores (off sync path).
// ---------------------------------------------------------------------------
__global__ __launch_bounds__(256, 1) void lstm_kernel(
    const _Float16* __restrict__ Whh,  // [4096][1024] quantized
    const float* __restrict__ bhh,     // [4096] quantized
    const _Float16* __restrict__ gx,   // packed [256][8][32][128][8]
    const float* __restrict__ c0,      // [64][1024]
    _Float16* __restrict__ hbuf,       // [8][2][8][1024] fp16
    float* __restrict__ out,           // [64][256][1024] ++ h_n ++ c_n
    unsigned* __restrict__ flags)      // [8][32]
{
  // Residency pin: force total regs/wave > 256 -> 1 wave/SIMD -> 1 block/CU.
  asm volatile("v_accvgpr_write_b32 a255, 0" ::: "a255");

  const int tid = threadIdx.x;
  const int lane = tid & 63;
  const int w = tid >> 6;
  const int cl = lane & 15, q = lane >> 4;
  const int g01 = (lane >> 3) & 1;
  const int c7 = lane & 7;

  const int grp = blockIdx.x & 7;    // batch octet
  const int rank = blockIdx.x >> 3;  // 32-column slice owner

  const int jbase = (rank << 5) + (w << 3);         // block/wave col base
  const int row0 = (g01 << 10) + jbase + c7;        // gates i/f
  const int row1 = ((g01 + 2) << 10) + jbase + c7;  // gates g/o

  // persistent B fragments: 2 tiles x 32 k-steps x 4 regs = 256 regs
  h8 B0[32], B1[32];
#pragma unroll
  for (int kt = 0; kt < 32; kt++) {
    B0[kt] = *(const h8*)(Whh + (size_t)row0 * 1024 + (kt << 5) + (q << 3));
    B1[kt] = *(const h8*)(Whh + (size_t)row1 * 1024 + (kt << 5) + (q << 3));
  }
  const float bh0 = bhh[row0], bh1 = bhh[row1];
  const int jc = jbase + c7;        // h column 0..1023
  const int lrow = ((q & 1) << 2);  // local batch row base (valid q<2)
  const bool writer = ((lane & 8) == 0) && (q < 2);

  float c_st[4], h_last[4];
#pragma unroll
  for (int r = 0; r < 4; r++) {
    c_st[r] = c0[((grp << 3) + lrow + r) * 1024 + jc];
    h_last[r] = 0.0f;
  }

  // LDS h stage: 8 rows x 1032 halves (pad +8: fragment reads arow*1032 are
  // conflict-free, verified in R6). Tail 256 halves: per-wave h-publication
  // tile (R13). rdy[16]: per-column-pair staged-step counters (monotone).
  __shared__ alignas(16) _Float16 hs[8 * 1032 + 4 * 64];
  __shared__ unsigned rdy[16];
  const int arow = cl & 7;
  const u64* hb64 = (const u64*)hbuf;  // [grp: 4096][buf: 2048] u64s
  _Float16* ts = hs + 8 * 1032 + w * 64;  // per-wave [8 rows][8 cols] tile

  // R14 staging: wave w owns column-pairs p = 4w..4w+3 (h cols [64p, 64p+64)).
  // Lane l: row = l>>4 (and +4), c16 = l&15 -> u64 col = p*16 + c16.
  // Global: 128B runs per 16 lanes; LDS: 4-way banks (same class as R10/R13).
  const int srow = lane >> 4;   // 0..3
  const int c16 = lane & 15;    // 0..15
  const size_t sbase =
      (size_t)grp * 4096 + (size_t)srow * 256 + (w << 6) + c16;
  _Float16* sl = hs + srow * 1032 + (w << 8) + (c16 << 2);

  unsigned* myflag = flags + (grp << 5) + rank;
  const u64* f2 = (const u64*)(flags + (grp << 5));  // 16 u64 per group
  const int w4 = w << 2;

  if (tid < 16) rdy[tid] = 0;
  __syncthreads();

  for (int t = 0; t < 256; t++) {
    // prefetch gx_t: one coalesced 16B load per lane (overlaps poll/stage)
    const h8 gv8 = *(const h8*)(
        gx +
        ((((size_t)t * 8 + grp) * 32 + rank) * 128 + ((w << 5) | (lane & 31))) *
            8);

    // ---- per-wave poll of OWN 4 pair-flags (8 producer ranks) ------------
    if (t) {
      const unsigned tt = (unsigned)t;
      int it = 0;
      for (;;) {
        u64 v = __hip_atomic_load(&f2[w4 + (lane & 3)], __ATOMIC_RELAXED,
                                  __HIP_MEMORY_SCOPE_AGENT);
        bool ok = ((unsigned)v >= tt) && ((unsigned)(v >> 32) >= tt);
        if (__ballot(ok) == ~0ull) break;
        if (++it > (1 << 14)) break;  // hang insurance (loudly wrong)
        __builtin_amdgcn_s_sleep(1);
      }
    }

    // ---- stage own 4 pairs (4KB/wave): 8x8B agent loads -> ds_write_b64 --
    {
      const u64* src = hb64 + sbase + (size_t)(t & 1) * 2048;
      u64 v0 = __hip_atomic_load(src + 0 * 16, __ATOMIC_RELAXED, __HIP_MEMORY_SCOPE_AGENT);
      u64 v1 = __hip_atomic_load(src + 1 * 16, __ATOMIC_RELAXED, __HIP_MEMORY_SCOPE_AGENT);
      u64 v2 = __hip_atomic_load(src + 2 * 16, __ATOMIC_RELAXED, __HIP_MEMORY_SCOPE_AGENT);
      u64 v3 = __hip_atomic_load(src + 3 * 16, __ATOMIC_RELAXED, __HIP_MEMORY_SCOPE_AGENT);
      u64 v4 = __hip_atomic_load(src + 1024 + 0 * 16, __ATOMIC_RELAXED, __HIP_MEMORY_SCOPE_AGENT);
      u64 v5 = __hip_atomic_load(src + 1024 + 1 * 16, __ATOMIC_RELAXED, __HIP_MEMORY_SCOPE_AGENT);
      u64 v6 = __hip_atomic_load(src + 1024 + 2 * 16, __ATOMIC_RELAXED, __HIP_MEMORY_SCOPE_AGENT);
      u64 v7 = __hip_atomic_load(src + 1024 + 3 * 16, __ATOMIC_RELAXED, __HIP_MEMORY_SCOPE_AGENT);
      *(u64*)(sl + 0 * 64) = v0;
      *(u64*)(sl + 1 * 64) = v1;
      *(u64*)(sl + 2 * 64) = v2;
      *(u64*)(sl + 3 * 64) = v3;
      *(u64*)(sl + 4 * 1032 + 0 * 64) = v4;
      *(u64*)(sl + 4 * 1032 + 1 * 64) = v5;
      *(u64*)(sl + 4 * 1032 + 2 * 64) = v6;
      *(u64*)(sl + 4 * 1032 + 3 * 64) = v7;
      asm volatile("s_waitcnt lgkmcnt(0)" ::: "memory");
      if (lane < 4) rdy[w4 + lane] = (unsigned)(t + 1);
    }

    // ---- consume pairs 0..15 (fixed order: B-frag indices compile-time) --
    f4 a0 = {}, a1 = {}, a2 = {}, a3 = {};
    const unsigned need = (unsigned)(t + 1);
#pragma unroll
    for (int i = 0; i < 16; i++) {
      if ((i >> 2) != w) {  // own pairs already staged + lgkm-drained
        int it = 0;
        while (*(volatile unsigned*)&rdy[i] < need) {
          if (++it > (1 << 16)) break;  // hang insurance (loudly wrong)
        }
        __builtin_amdgcn_sched_barrier(0);  // keep frag reads after the gate
      }
      const _Float16* fb = hs + arow * 1032 + (i << 6) + (q << 3);
      h8 av0 = *(const h8*)fb;
      h8 av1 = *(const h8*)(fb + 32);
      a0 = MFMA16(av0, B0[2 * i], a0);
      a2 = MFMA16(av0, B1[2 * i], a2);
      a1 = MFMA16(av1, B0[2 * i + 1], a1);
      a3 = MFMA16(av1, B1[2 * i + 1], a3);
    }
    f4 g0 = a0 + a1;
    f4 g1 = a2 + a3;

    _Float16* hbw = hbuf + (size_t)grp * 16384 + ((t + 1) & 1) * 8192;
#pragma unroll
    for (int r = 0; r < 4; r++) {
      float gv0 = fxp((float)gv8[r] + fxp(g0[r] + bh0));      // i or f
      float gv1 = fxp((float)gv8[4 + r] + fxp(g1[r] + bh1));  // g or o
      float s0 = fxp_rnd(hsig(gv0));                        // in [0,1]
      float s1t = fxp_rnd(fminf(fmaxf(gv1, -1.0f), 1.0f));  // in [-1,1]
      float s1s = fxp_rnd(hsig(gv1));
      float s1 = (lane & 8) ? s1s : s1t;
      float p0 = __shfl_xor(s0, 8);
      float p1 = __shfl_xor(s1, 8);
      float iv = writer ? s0 : p0;
      float fv = writer ? p0 : s0;
      float gv = writer ? s1 : p1;
      float ov = writer ? p1 : s1;
      float cn = fxp(fv * c_st[r] + iv * gv);
      c_st[r] = cn;
      float hn = fxp_rnd(ov * fminf(fmaxf(cn, -1.0f), 1.0f));  // in [-1,1]
      h_last[r] = hn;
      // R13: deposit h into the per-wave LDS tile (2 lanes/bank, free)
      if (writer) ts[(lrow + r) * 8 + c7] = (_Float16)hn;
    }
    // wave-local: wait for the tile, lanes 0-15 transpose-read (b64) and
    // issue 16 contiguous 8B agent stores (two lanes = 16B run per row).
    asm volatile("s_waitcnt lgkmcnt(0)" ::: "memory");
    if (lane < 16) {
      u64 hv = *(const u64*)(ts + (lane >> 1) * 8 + ((lane & 1) << 2));
      __hip_atomic_store(
          (u64*)&hbw[(lane >> 1) * 1024 + jbase + ((lane & 1) << 2)], hv,
          __ATOMIC_RELAXED, __HIP_MEMORY_SCOPE_AGENT);
    }
    __syncthreads();  // A: drains h stores; also fences LDS reuse for t+1
    if (tid == 0)
      __hip_atomic_store(myflag, (unsigned)(t + 1), __ATOMIC_RELAXED,
                         __HIP_MEMORY_SCOPE_AGENT);
    // out stores after the flag: drain overlaps the next step's poll/stage
    if (writer) {
#pragma unroll
      for (int r = 0; r < 4; r++)
        __builtin_nontemporal_store(
            h_last[r],
            &out[((size_t)((grp << 3) + lrow + r) * 256 + t) * 1024 + jc]);
    }
  }

  if (writer) {
#pragma unroll
    for (int r = 0; r < 4; r++) {
      out[16777216 + (size_t)((grp << 3) + lrow + r) * 1024 + jc] = h_last[r];
      out[16777216 + 65536 + (size_t)((grp << 3) + lrow + r) * 1024 + jc] =
          c_st[r];
    }
  }
}

// ---------------------------------------------------------------------------
extern "C" void kernel_launch(void* const* d_in, const int* in_sizes, int n_in,
                              void* d_out, int out_size, void* d_ws,
                              size_t ws_size, hipStream_t stream) {
  const float* x    = (const float*)d_in[0];
  const float* w_ih = (const float*)d_in[1];
  const float* w_hh = (const float*)d_in[2];
  const float* b_ih = (const float*)d_in[3];
  const float* b_hh = (const float*)d_in[4];
  const float* h0   = (const float*)d_in[5];
  const float* c0   = (const float*)d_in[6];
  float* out = (float*)d_out;

  // workspace layout (bytes); total ~156.3 MB
  char* ws = (char*)d_ws;
  unsigned* flags = (unsigned*)ws;                    // [8][32] u32 = 1 KB
  _Float16* hbuf  = (_Float16*)(ws + 2048);           // 8*2*8*1024*2 = 256 KB
  _Float16* whhq  = (_Float16*)(ws + 264192);         // 8 MB
  _Float16* wihq  = (_Float16*)(ws + 8652800);        // 4 MB
  float*    bihq  = (float*)(ws + 12847104);          // 16 KB
  float*    bhhq  = (float*)(ws + 12863488);          // 16 KB
  _Float16* xq    = (_Float16*)(ws + 12879872);       // 16 MB
  _Float16* gxb   = (_Float16*)(ws + 29657088);       // 128 MB packed

  hipMemsetAsync(flags, 0, 2048, stream);
  qf16_kernel<<<dim3(4096), 256, 0, stream>>>(w_hh, whhq, 4194304 / 4);
  qf16_kernel<<<dim3(2048), 256, 0, stream>>>(w_ih, wihq, 2097152 / 4);
  qx_kernel<<<dim3(8192), 256, 0, stream>>>(x, xq);
  qh0_kernel<<<dim3(64), 256, 0, stream>>>(h0, hbuf);
  qf32_kernel<<<dim3(4), 256, 0, stream>>>(b_ih, bihq, 4096 / 4);
  qf32_kernel<<<dim3(4), 256, 0, stream>>>(b_hh, bhhq, 4096 / 4);
  gemm_gx_kernel<<<dim3(128, 32), 256, 0, stream>>>(xq, wihq, bihq, gxb);
  lstm_kernel<<<dim3(256), 256, 0, stream>>>(whhq, bhhq, gxb, c0, hbuf, out,
                                             flags);
}

// Round 5
// 1076.402 us; speedup vs baseline: 1.2714x; 1.2714x over previous
//
#include <hip/hip_runtime.h>
#include <stdint.h>

// ---------------------------------------------------------------------------
// FixedPointLSTM (B=64, T=256, I=512, H=1024), fixed-point Q8.8 with hard
// activations. All fxp grid values are exactly representable in fp16; fp16
// MFMA with fp32 accumulate matches the numpy reference to ~1 grid step.
//
// R15 = R13 (verified 862 us lstm / 1063 us total) + cheap out-store acks.
// History: R11 (sc0 comm) FAILED; R12 (placement shuffle) -30us regress;
// R13 (coalesced h publication) +7us win; R14 (chunk-granular pipeline)
// -315us REGRESS (reverted). Sync-structure changes are 0-for-4; the R10/R13
// skeleton (per-block flags, w0 poll, 3 barriers, barrier-then-flag) stays.
// R15 attacks a newly-identified vmcnt-FIFO x store-ack interaction:
//  1) out stores were NONTEMPORAL (no-allocate -> ack beyond L3, ~2000cyc).
//     Issued after the flag, their acks landed on the NEXT step's critical
//     path: w1-3's stage vmcnt(0) and w0's poll vmcnt(0) (FIFO) waited for
//     them every step. Now plain cached stores (ack from local L2; each rank
//     writes exclusive aligned 128B runs; kernel-end writeback publishes).
//  2) w0's gx HBM prefetch moves to after its poll succeeds (was before the
//     poll -> first poll iteration waited its ~900cyc HBM ack). Still
//     overlaps barrier B + stage, drains at barrier C. Flag timing untouched
//     (R12's mistake was delaying the flag; R15 does not).
// ---------------------------------------------------------------------------

typedef _Float16 h8 __attribute__((ext_vector_type(8)));
typedef _Float16 h4 __attribute__((ext_vector_type(4)));
typedef float f4 __attribute__((ext_vector_type(4)));
typedef unsigned long long u64;

#define MFMA16(a, b, c) __builtin_amdgcn_mfma_f32_16x16x32_f16(a, b, c, 0, 0, 0)

__device__ __forceinline__ float fxp(float x) {
  float q = rintf(x * 256.0f) * 0.00390625f;
  return fminf(fmaxf(q, -128.0f), 127.99609375f);
}

// round-only: for values provably in [-128, 127.996] the clamp is a no-op.
__device__ __forceinline__ float fxp_rnd(float x) {
  return rintf(x * 256.0f) * 0.00390625f;
}

__device__ __forceinline__ float hsig(float x) {
  return fminf(fmaxf(x / 6.0f + 0.5f, 0.0f), 1.0f);  // IEEE div to match np
}

// ---- quantize fp32 -> fxp grid, store fp16 ---------------------------------
__global__ void qf16_kernel(const float* __restrict__ in,
                            _Float16* __restrict__ out, int n4) {
  int i = blockIdx.x * 256 + threadIdx.x;
  if (i < n4) {
    float4 v = ((const float4*)in)[i];
    h4 o;
    o[0] = (_Float16)fxp(v.x); o[1] = (_Float16)fxp(v.y);
    o[2] = (_Float16)fxp(v.z); o[3] = (_Float16)fxp(v.w);
    ((h4*)out)[i] = o;
  }
}

// quantize + transpose x: in [64][256][512] -> rows m = t*64+b, [16384][512]
__global__ void qx_kernel(const float* __restrict__ in,
                          _Float16* __restrict__ out) {
  int i4 = blockIdx.x * 256 + threadIdx.x;  // over 16384*128 float4s
  int col4 = i4 & 127;
  int row = i4 >> 7;  // b*256 + t
  int b = row >> 8, tt = row & 255;
  float4 v = ((const float4*)in)[i4];
  h4 o;
  o[0] = (_Float16)fxp(v.x); o[1] = (_Float16)fxp(v.y);
  o[2] = (_Float16)fxp(v.z); o[3] = (_Float16)fxp(v.w);
  ((h4*)out)[(size_t)((tt << 6) + b) * 128 + col4] = o;
}

__global__ void qf32_kernel(const float* __restrict__ in,
                            float* __restrict__ out, int n4) {
  int i = blockIdx.x * 256 + threadIdx.x;
  if (i < n4) {
    float4 v = ((const float4*)in)[i];
    float4 o;
    o.x = fxp(v.x); o.y = fxp(v.y); o.z = fxp(v.z); o.w = fxp(v.w);
    ((float4*)out)[i] = o;
  }
}

// h0 -> hbuf buffer 0, layout [grp=8][buf=2][row=8][1024] fp16
__global__ void qh0_kernel(const float* __restrict__ in,
                           _Float16* __restrict__ hbuf) {
  int i = blockIdx.x * 256 + threadIdx.x;  // over 64*1024/4
  int col4 = i & 255, b = i >> 8;
  float4 v = ((const float4*)in)[i];
  h4 o;
  o[0] = (_Float16)fxp(v.x); o[1] = (_Float16)fxp(v.y);
  o[2] = (_Float16)fxp(v.z); o[3] = (_Float16)fxp(v.w);
  *(h4*)(hbuf + (size_t)(b >> 3) * 16384 + (b & 7) * 1024 + col4 * 4) = o;
}

// ---- async global->LDS helper (width 16B; LDS dest = wave-uniform base) ----
__device__ __forceinline__ void gload_lds16(const _Float16* g, _Float16* l) {
  __builtin_amdgcn_global_load_lds(
      (const __attribute__((address_space(1))) uint32_t*)g,
      (__attribute__((address_space(3))) uint32_t*)l, 16, 0, 0);
}

// ---------------------------------------------------------------------------
// gx = fxp(x_q @ w_ih_q^T + b_ih_q), packed [T=256][oct=8][rank=32][slot=128][8]
// fp16 (128 MB). slot = (w<<5)|(qh<<4)|(gate&1)<<3|(j&7); per-entry 8 fp16 =
// [tile0 r=0..3 | tile1 r=0..3], tile = gate>>1, r = b&3, qh = (b>>2)&1.
// ---------------------------------------------------------------------------
__global__ __launch_bounds__(256) void gemm_gx_kernel(
    const _Float16* __restrict__ Xq,   // [16384][512], m = t*64+b
    const _Float16* __restrict__ Wih,  // [4096][512]
    const float* __restrict__ bih,     // [4096]
    _Float16* __restrict__ gx)         // packed, see above
{
  __shared__ _Float16 As[128 * 32];
  __shared__ _Float16 Bs[128 * 32];
  const int tid = threadIdx.x;
  const int lane = tid & 63;
  const int w = tid >> 6;
  const int wm = (w >> 1) * 64;
  const int wn = (w & 1) * 64;
  const int m0 = blockIdx.x * 128;
  const int n0 = blockIdx.y * 128;
  const int cl = lane & 15, q = lane >> 4;

  f4 acc[4][4] = {};

  for (int k0 = 0; k0 < 512; k0 += 32) {
#pragma unroll
    for (int i = 0; i < 2; i++) {
      int idx = i * 256 + tid;
      int row = idx >> 2;
      int kc = (idx & 3) << 3;
      int wbase = (i * 256 + (tid & 192)) << 3;  // wave-uniform LDS base
      gload_lds16(Xq + (size_t)(m0 + row) * 512 + k0 + kc, As + wbase);
      gload_lds16(Wih + (size_t)(n0 + row) * 512 + k0 + kc, Bs + wbase);
    }
    __syncthreads();
    h8 af[4], bf[4];
#pragma unroll
    for (int mt = 0; mt < 4; mt++)
      af[mt] = *(const h8*)(As + (wm + mt * 16 + cl) * 32 + q * 8);
#pragma unroll
    for (int nt = 0; nt < 4; nt++)
      bf[nt] = *(const h8*)(Bs + (wn + nt * 16 + cl) * 32 + q * 8);
#pragma unroll
    for (int mt = 0; mt < 4; mt++)
#pragma unroll
      for (int nt = 0; nt < 4; nt++)
        acc[mt][nt] = MFMA16(af[mt], bf[nt], acc[mt][nt]);
    __syncthreads();
  }

  const int g = n0 >> 10;  // whole n-block lies in one gate
  const int tile = g >> 1, g1 = g & 1;
#pragma unroll
  for (int nt = 0; nt < 4; nt++) {
    const int n = n0 + wn + nt * 16 + cl;
    const float bv = bih[n];
    const int j = n & 1023;
    const int rank = j >> 5, wq = (j >> 3) & 3, c7 = j & 7;
#pragma unroll
    for (int mt = 0; mt < 4; mt++) {
      const int m = m0 + wm + mt * 16 + q * 4;  // 4-aligned
      const int b = m & 63, tt = m >> 6;
      const int oct = b >> 3, qh = (b >> 2) & 1;
      const int slot = (wq << 5) | (qh << 4) | (g1 << 3) | c7;
      h4 pk;
#pragma unroll
      for (int r = 0; r < 4; r++) pk[r] = (_Float16)fxp(acc[mt][nt][r] + bv);
      *(h4*)(gx + ((((size_t)tt * 8 + oct) * 32 + rank) * 128 + slot) * 8 +
             tile * 4) = pk;
    }
  }
}

// ---------------------------------------------------------------------------
// Persistent recurrence. 256 blocks x 256 threads, a255 pin -> 1 block/CU ->
// all blocks co-resident. Block = (grp = blockIdx&7, rank = blockIdx>>3);
// group owns batch rows 8g..8g+7; rank owns h-cols rank*32..+31 x 4 gates
// (128 W_hh rows in regs). Per step (R13 protocol, R15 ack hygiene):
//   [w1-3] gx prefetch -> w0 polls 32 per-block flags (no outstanding VMEM)
//   -> [w0] gx prefetch -> barrier B -> stage 8x8B coalesced agent loads ->
//   ds_write_b64 (4-way banks) -> barrier C -> MFMA -> gates -> h tile to
//   LDS -> transpose-read -> 16x8B agent stores/wave -> barrier A (drains h)
//   -> tid0 flag -> out stores (plain cached; ack from local L2).
// ---------------------------------------------------------------------------
__global__ __launch_bounds__(256, 1) void lstm_kernel(
    const _Float16* __restrict__ Whh,  // [4096][1024] quantized
    const float* __restrict__ bhh,     // [4096] quantized
    const _Float16* __restrict__ gx,   // packed [256][8][32][128][8]
    const float* __restrict__ c0,      // [64][1024]
    _Float16* __restrict__ hbuf,       // [8][2][8][1024] fp16
    float* __restrict__ out,           // [64][256][1024] ++ h_n ++ c_n
    unsigned* __restrict__ flags)      // [8][32]
{
  // Residency pin: force total regs/wave > 256 -> 1 wave/SIMD -> 1 block/CU.
  asm volatile("v_accvgpr_write_b32 a255, 0" ::: "a255");

  const int tid = threadIdx.x;
  const int lane = tid & 63;
  const int w = tid >> 6;
  const int cl = lane & 15, q = lane >> 4;
  const int g01 = (lane >> 3) & 1;
  const int c7 = lane & 7;

  const int grp = blockIdx.x & 7;    // batch octet
  const int rank = blockIdx.x >> 3;  // 32-column slice owner

  const int jbase = (rank << 5) + (w << 3);         // block/wave col base
  const int row0 = (g01 << 10) + jbase + c7;        // gates i/f
  const int row1 = ((g01 + 2) << 10) + jbase + c7;  // gates g/o

  // persistent B fragments: 2 tiles x 32 k-steps x 4 regs = 256 regs
  h8 B0[32], B1[32];
#pragma unroll
  for (int kt = 0; kt < 32; kt++) {
    B0[kt] = *(const h8*)(Whh + (size_t)row0 * 1024 + (kt << 5) + (q << 3));
    B1[kt] = *(const h8*)(Whh + (size_t)row1 * 1024 + (kt << 5) + (q << 3));
  }
  const float bh0 = bhh[row0], bh1 = bhh[row1];
  const int jc = jbase + c7;        // h column 0..1023
  const int lrow = ((q & 1) << 2);  // local batch row base (valid q<2)
  const bool writer = ((lane & 8) == 0) && (q < 2);

  float c_st[4], h_last[4];
#pragma unroll
  for (int r = 0; r < 4; r++) {
    c_st[r] = c0[((grp << 3) + lrow + r) * 1024 + jc];
    h_last[r] = 0.0f;
  }

  // LDS h stage: 8 rows x 1032 halves (pad +8: fragment reads arow*1032 are
  // conflict-free, verified in R6). Staging: thread (row=tid>>5, c=tid&31)
  // loads u64s c+32j of its row (coalesced 256B/32 lanes), writes LDS at
  // row*1032 + 4c + 128j halves -> 4-way banks. Tail 256 halves: per-wave
  // 64-half h-publication scratch tile (R13).
  __shared__ alignas(16) _Float16 hs[8 * 1032 + 4 * 64];
  const int arow = cl & 7;
  const u64* hb64 = (const u64*)hbuf;  // [grp: 4096][buf: 2048] u64s
  const size_t lsrc = (size_t)grp * 4096 + (size_t)((tid >> 5) << 8) + (tid & 31);
  _Float16* ldst = hs + (tid >> 5) * 1032 + ((tid & 31) << 2);
  _Float16* ts = hs + 8 * 1032 + w * 64;  // per-wave [8 rows][8 cols] tile

  unsigned* myflag = flags + (grp << 5) + rank;
  const u64* f2 = (const u64*)(flags + (grp << 5));  // 16 u64 per group

  for (int t = 0; t < 256; t++) {
    const size_t gxoff =
        ((((size_t)t * 8 + grp) * 32 + rank) * 128 + ((w << 5) | (lane & 31))) *
        8;
    h8 gv8;
    // w1-3 (and everyone at t=0): prefetch gx before the poll barrier; it
    // drains at barrier C. w0 at t>0 defers until after its poll so the
    // poll's vmcnt(0) (FIFO) never waits on this HBM read.
    if (w != 0 || t == 0) gv8 = *(const h8*)(gx + gxoff);

    if (t) {
      if (w == 0) {
        const unsigned tt = (unsigned)t;
        int it = 0;
        for (;;) {
          u64 v = __hip_atomic_load(&f2[lane & 15], __ATOMIC_RELAXED,
                                    __HIP_MEMORY_SCOPE_AGENT);
          bool ok = ((unsigned)v >= tt) && ((unsigned)(v >> 32) >= tt);
          if (__ballot(ok) == ~0ull) break;
          if (++it > (1 << 14)) break;  // hang insurance (loudly wrong)
          __builtin_amdgcn_s_sleep(1);
        }
        gv8 = *(const h8*)(gx + gxoff);  // post-poll; overlaps B + stage
      }
      __syncthreads();  // B
    }

    // ---- stage h_t (16KB): 8 coalesced 8B agent loads -> ds_write_b64 ----
    {
      const u64* src = hb64 + lsrc + (size_t)(t & 1) * 2048;
      u64 v0 = __hip_atomic_load(src + 0 * 32, __ATOMIC_RELAXED, __HIP_MEMORY_SCOPE_AGENT);
      u64 v1 = __hip_atomic_load(src + 1 * 32, __ATOMIC_RELAXED, __HIP_MEMORY_SCOPE_AGENT);
      u64 v2 = __hip_atomic_load(src + 2 * 32, __ATOMIC_RELAXED, __HIP_MEMORY_SCOPE_AGENT);
      u64 v3 = __hip_atomic_load(src + 3 * 32, __ATOMIC_RELAXED, __HIP_MEMORY_SCOPE_AGENT);
      u64 v4 = __hip_atomic_load(src + 4 * 32, __ATOMIC_RELAXED, __HIP_MEMORY_SCOPE_AGENT);
      u64 v5 = __hip_atomic_load(src + 5 * 32, __ATOMIC_RELAXED, __HIP_MEMORY_SCOPE_AGENT);
      u64 v6 = __hip_atomic_load(src + 6 * 32, __ATOMIC_RELAXED, __HIP_MEMORY_SCOPE_AGENT);
      u64 v7 = __hip_atomic_load(src + 7 * 32, __ATOMIC_RELAXED, __HIP_MEMORY_SCOPE_AGENT);
      *(u64*)(ldst + 0 * 128) = v0;
      *(u64*)(ldst + 1 * 128) = v1;
      *(u64*)(ldst + 2 * 128) = v2;
      *(u64*)(ldst + 3 * 128) = v3;
      *(u64*)(ldst + 4 * 128) = v4;
      *(u64*)(ldst + 5 * 128) = v5;
      *(u64*)(ldst + 6 * 128) = v6;
      *(u64*)(ldst + 7 * 128) = v7;
    }
    __syncthreads();  // C

    f4 a0 = {}, a1 = {}, a2 = {}, a3 = {};
#pragma unroll
    for (int kt = 0; kt < 32; kt++) {
      h8 av = *(const h8*)(hs + arow * 1032 + (kt << 5) + (q << 3));
      if (kt & 1) { a1 = MFMA16(av, B0[kt], a1); a3 = MFMA16(av, B1[kt], a3); }
      else        { a0 = MFMA16(av, B0[kt], a0); a2 = MFMA16(av, B1[kt], a2); }
    }
    f4 g0 = a0 + a1;
    f4 g1 = a2 + a3;

    _Float16* hbw = hbuf + (size_t)grp * 16384 + ((t + 1) & 1) * 8192;
#pragma unroll
    for (int r = 0; r < 4; r++) {
      float gv0 = fxp((float)gv8[r] + fxp(g0[r] + bh0));      // i or f
      float gv1 = fxp((float)gv8[4 + r] + fxp(g1[r] + bh1));  // g or o
      float s0 = fxp_rnd(hsig(gv0));                        // in [0,1]
      float s1t = fxp_rnd(fminf(fmaxf(gv1, -1.0f), 1.0f));  // in [-1,1]
      float s1s = fxp_rnd(hsig(gv1));
      float s1 = (lane & 8) ? s1s : s1t;
      float p0 = __shfl_xor(s0, 8);
      float p1 = __shfl_xor(s1, 8);
      float iv = writer ? s0 : p0;
      float fv = writer ? p0 : s0;
      float gv = writer ? s1 : p1;
      float ov = writer ? p1 : s1;
      float cn = fxp(fv * c_st[r] + iv * gv);
      c_st[r] = cn;
      float hn = fxp_rnd(ov * fminf(fmaxf(cn, -1.0f), 1.0f));  // in [-1,1]
      h_last[r] = hn;
      // R13: deposit h into the per-wave LDS tile instead of a scattered 2B
      // agent store (2 lanes/bank, free).
      if (writer) ts[(lrow + r) * 8 + c7] = (_Float16)hn;
    }
    // wave-local: ds ops of one wave complete in order; wait for the tile,
    // then lanes 0-15 transpose-read (b64, 16 distinct bank-pairs) and issue
    // 16 contiguous 8B agent stores (two lanes = 16B run per row).
    asm volatile("s_waitcnt lgkmcnt(0)" ::: "memory");
    if (lane < 16) {
      u64 hv = *(const u64*)(ts + (lane >> 1) * 8 + ((lane & 1) << 2));
      __hip_atomic_store(
          (u64*)&hbw[(lane >> 1) * 1024 + jbase + ((lane & 1) << 2)], hv,
          __ATOMIC_RELAXED, __HIP_MEMORY_SCOPE_AGENT);
    }
    __syncthreads();  // A: drains the h stores (out stores not yet issued)
    if (tid == 0)
      __hip_atomic_store(myflag, (unsigned)(t + 1), __ATOMIC_RELAXED,
                         __HIP_MEMORY_SCOPE_AGENT);
    // out stores after the flag, PLAIN cached (R15): ack from local L2, so
    // the next step's vmcnt(0) waits (w0 poll, stage) don't eat an HBM ack.
    // Each rank writes exclusive 128B-aligned runs -> no L2 line ping-pong.
    if (writer) {
#pragma unroll
      for (int r = 0; r < 4; r++)
        out[((size_t)((grp << 3) + lrow + r) * 256 + t) * 1024 + jc] =
            h_last[r];
    }
  }

  if (writer) {
#pragma unroll
    for (int r = 0; r < 4; r++) {
      out[16777216 + (size_t)((grp << 3) + lrow + r) * 1024 + jc] = h_last[r];
      out[16777216 + 65536 + (size_t)((grp << 3) + lrow + r) * 1024 + jc] =
          c_st[r];
    }
  }
}

// ---------------------------------------------------------------------------
extern "C" void kernel_launch(void* const* d_in, const int* in_sizes, int n_in,
                              void* d_out, int out_size, void* d_ws,
                              size_t ws_size, hipStream_t stream) {
  const float* x    = (const float*)d_in[0];
  const float* w_ih = (const float*)d_in[1];
  const float* w_hh = (const float*)d_in[2];
  const float* b_ih = (const float*)d_in[3];
  const float* b_hh = (const float*)d_in[4];
  const float* h0   = (const float*)d_in[5];
  const float* c0   = (const float*)d_in[6];
  float* out = (float*)d_out;

  // workspace layout (bytes); total ~156.3 MB
  char* ws = (char*)d_ws;
  unsigned* flags = (unsigned*)ws;                    // [8][32] u32 = 1 KB
  _Float16* hbuf  = (_Float16*)(ws + 2048);           // 8*2*8*1024*2 = 256 KB
  _Float16* whhq  = (_Float16*)(ws + 264192);         // 8 MB
  _Float16* wihq  = (_Float16*)(ws + 8652800);        // 4 MB
  float*    bihq  = (float*)(ws + 12847104);          // 16 KB
  float*    bhhq  = (float*)(ws + 12863488);          // 16 KB
  _Float16* xq    = (_Float16*)(ws + 12879872);       // 16 MB
  _Float16* gxb   = (_Float16*)(ws + 29657088);       // 128 MB packed

  hipMemsetAsync(flags, 0, 2048, stream);
  qf16_kernel<<<dim3(4096), 256, 0, stream>>>(w_hh, whhq, 4194304 / 4);
  qf16_kernel<<<dim3(2048), 256, 0, stream>>>(w_ih, wihq, 2097152 / 4);
  qx_kernel<<<dim3(8192), 256, 0, stream>>>(x, xq);
  qh0_kernel<<<dim3(64), 256, 0, stream>>>(h0, hbuf);
  qf32_kernel<<<dim3(4), 256, 0, stream>>>(b_ih, bihq, 4096 / 4);
  qf32_kernel<<<dim3(4), 256, 0, stream>>>(b_hh, bhhq, 4096 / 4);
  gemm_gx_kernel<<<dim3(128, 32), 256, 0, stream>>>(xq, wihq, bihq, gxb);
  lstm_kernel<<<dim3(256), 256, 0, stream>>>(whhq, bhhq, gxb, c0, hbuf, out,
                                             flags);
}